// Round 7
// baseline (91.304 us; speedup 1.0000x reference)
//
#include <hip/hip_runtime.h>
#include <stdint.h>

// ONNX NonMaxSuppression: B=8, N=16384, C=80, MAX_OUT=50
// nms_fast, one block per (b,c):
//   phase A: streaming score scan; push key (score<<32|invidx<<18|slot) + box
//            index of candidates above fixed optimistic cutoff
//   phase A2: issue slot-indexed box loads (latency hidden under the sort)
//   phase B: bitonic sort, BARRIER-LIGHT: stages with jj<=64 are wave-local
//            (wave64 lockstep + in-order per-wave LDS => no __syncthreads);
//            only the 3 cross-wave stages (jj>=128) are barriered
//   phase B2: write gathered boxes to slot-indexed LDS SoA
//   phase D: wave-0 sorted walk, alive mask replicated per lane, column
//            boxes in registers, per-selection register IoU + __ballot
// Exactness: overflow or exhaustion-with-remainder flags the lane in d_ws;
// gated nms_slow (verified adaptive 2-pass kernel) re-solves those lanes.

#define NMS_B 8
#define NMS_N 16384
#define NMS_C 80
#define NMS_MAX_OUT 50
#define NTHREADS 256

// fast kernel
#define OPT_THR 0.9765625f   // E[cnt]=384, sigma~19.4; FCAP=512 -> +6.6 sigma
#define FCAP 512
#define WMAX (FCAP / 64)     // 8 alive words

// slow (fallback) kernel
#define NBUCK 256
#define SCAP 1024
#define T_MIN 320

typedef unsigned long long u64;
typedef unsigned int u32;

__device__ __forceinline__ float iou_exact(float4 A, float areaA, float4 Bx) {
    float x1 = fmaxf(A.x, Bx.x);
    float y1 = fmaxf(A.y, Bx.y);
    float x2 = fminf(A.z, Bx.z);
    float y2 = fminf(A.w, Bx.w);
    float dx = fmaxf(__fsub_rn(x2, x1), 0.0f);
    float dy = fmaxf(__fsub_rn(y2, y1), 0.0f);
    if (!(dx > 0.0f && dy > 0.0f)) return 0.0f;   // inter==0 -> iou==0 exactly
    float inter = __fmul_rn(dx, dy);
    float areaB = __fmul_rn(__fsub_rn(Bx.z, Bx.x), __fsub_rn(Bx.w, Bx.y));
    float uni   = __fsub_rn(__fadd_rn(areaA, areaB), inter);
    return __fdiv_rn(inter, fmaxf(uni, 1e-9f));
}

// same chain, areaB precomputed (value-identical: areaB = (x2-x1)*(y2-y1))
__device__ __forceinline__ float iou_pre(float4 A, float areaA, float4 Bx, float areaB) {
    float x1 = fmaxf(A.x, Bx.x);
    float y1 = fmaxf(A.y, Bx.y);
    float x2 = fminf(A.z, Bx.z);
    float y2 = fminf(A.w, Bx.w);
    float dx = fmaxf(__fsub_rn(x2, x1), 0.0f);
    float dy = fmaxf(__fsub_rn(y2, y1), 0.0f);
    if (!(dx > 0.0f && dy > 0.0f)) return 0.0f;
    float inter = __fmul_rn(dx, dy);
    float uni   = __fsub_rn(__fadd_rn(areaA, areaB), inter);
    return __fdiv_rn(inter, fmaxf(uni, 1e-9f));
}

template <bool OUT64>
__global__ __launch_bounds__(NTHREADS) void nms_fast(
    const float* __restrict__ boxes,
    const float* __restrict__ scores,
    const int* __restrict__ p_maxout,
    const float* __restrict__ p_iou,
    const float* __restrict__ p_sthr,
    void* __restrict__ out_raw,
    int* __restrict__ flags)
{
    __shared__ u64   skey[FCAP];
    __shared__ int   sn[FCAP];
    __shared__ float sx[FCAP], sy[FCAP], sz[FCAP], sw[FCAP];
    __shared__ int   s_cnt, s_total;

    const int tid = threadIdx.x;
    const int bc  = blockIdx.x;
    const int b   = bc / NMS_C;
    const int c   = bc % NMS_C;

    const float score_thr = p_sthr[0];
    const float iou_thr   = p_iou[0];
    int maxo = p_maxout[0];
    if (maxo > NMS_MAX_OUT) maxo = NMS_MAX_OUT;
    if (maxo < 0) maxo = 0;

    int*       out32 = (int*)out_raw       + (size_t)bc * NMS_MAX_OUT * 3;
    long long* out64 = (long long*)out_raw + (size_t)bc * NMS_MAX_OUT * 3;
    for (int i = tid; i < NMS_MAX_OUT * 3; i += NTHREADS) {
        if (OUT64) out64[i] = -1LL; else out32[i] = -1;
    }

    if (tid == 0) { s_cnt = 0; s_total = 0; }
    __syncthreads();

    const float4* sc4     = (const float4*)(scores + ((size_t)b * NMS_C + c) * NMS_N);
    const float4* boxes_b = (const float4*)(boxes + (size_t)b * NMS_N * 4);

    // ---- phase A: streaming score scan ----
    float4 av[16];
    #pragma unroll
    for (int u = 0; u < 16; ++u) av[u] = sc4[u * NTHREADS + tid];

    int local_total = 0;
    #pragma unroll
    for (int u = 0; u < 16; ++u) {
        const int i = u * NTHREADS + tid;
        float ss[4] = {av[u].x, av[u].y, av[u].z, av[u].w};
        #pragma unroll
        for (int j = 0; j < 4; ++j) {
            float s = ss[j];
            bool cand = (s > score_thr);
            local_total += cand ? 1 : 0;
            if (cand && s >= OPT_THR) {          // rare (~2.3%)
                int n = i * 4 + j;
                int p = atomicAdd(&s_cnt, 1);
                if (p < FCAP) {
                    skey[p] = ((u64)__float_as_uint(s) << 32)
                            | ((u64)(NMS_N - 1 - n) << 18)
                            | (u64)p;            // 9-bit slot
                    sn[p] = n;
                }
            }
        }
    }
    atomicAdd(&s_total, local_total);
    __syncthreads();

    const int  m        = (s_cnt < FCAP) ? s_cnt : FCAP;
    const bool overflow = (s_cnt > FCAP);
    const int  rem      = s_total - s_cnt;   // candidates below optimistic cut

    if (overflow) {                          // uniform block-wide bail
        if (tid == 0) flags[bc] = 1;
        return;
    }

    // ---- phase A2: issue slot-indexed box loads (hide under the sort) ----
    const int slot0 = tid, slot1 = tid + 256;
    const int n0 = (slot0 < m) ? sn[slot0] : 0;
    const int n1 = (slot1 < m) ? sn[slot1] : 0;
    float4 g0 = boxes_b[n0];                 // in flight during phase B
    float4 g1 = boxes_b[n1];

    // wave-local pad of this wave's 128-element sort segment
    {
        const int w = tid >> 6, s = tid & 63;
        const int i0 = 128 * w + s, i1 = i0 + 64;
        if (i0 >= m) skey[i0] = 0ull;
        if (i1 >= m) skey[i1] = 0ull;
    }

    // ---- phase B: bitonic sort desc, barrier-light ----
    // jj<=64 stages stay inside each wave's private 128-elem segment:
    // i = 2jj(t/jj)+(t%jj) = 128w + 2jj(s/jj)+(s%jj) for t=64w+s, jj|64.
    // wave64 lockstep + in-order per-wave LDS => no block barrier needed.
    for (int kk = 2; kk <= FCAP; kk <<= 1) {
        for (int jj = kk >> 1; jj > 0; jj >>= 1) {
            const bool cross = (jj >= 128);
            if (cross) __syncthreads();
            const int i  = 2 * jj * (tid / jj) + (tid % jj);
            const int p2 = i + jj;
            const bool dirDesc = ((i & kk) == 0);
            u64 a = skey[i], bkey = skey[p2];
            bool swapq = dirDesc ? (a < bkey) : (a > bkey);
            if (swapq) { skey[i] = bkey; skey[p2] = a; }
            if (cross) __syncthreads();
            else __builtin_amdgcn_sched_barrier(0);
        }
    }

    // ---- phase B2: land gathered boxes into slot-indexed SoA ----
    sx[slot0] = g0.x; sy[slot0] = g0.y; sz[slot0] = g0.z; sw[slot0] = g0.w;
    sx[slot1] = g1.x; sy[slot1] = g1.y; sz[slot1] = g1.z; sw[slot1] = g1.w;
    __syncthreads();

    if (tid >= 64) return;                   // waves 1..3 retire
    const int lane = tid;

    // ---- phase D: sorted walk, alive mask replicated in every lane ----
    // hoist this lane's column boxes + areas into registers (rank-indexed)
    float4 bxc[WMAX];
    float  areaBc[WMAX];
    #pragma unroll
    for (int w2 = 0; w2 < WMAX; ++w2) {
        const int j = w2 * 64 + lane;
        const int sl = (int)(skey[j] & 0x1FFull);   // pad -> slot 0 (masked later)
        bxc[w2] = make_float4(sx[sl], sy[sl], sz[sl], sw[sl]);
        areaBc[w2] = __fmul_rn(__fsub_rn(bxc[w2].z, bxc[w2].x),
                               __fsub_rn(bxc[w2].w, bxc[w2].y));
    }

    u64 aliveW[WMAX];
    #pragma unroll
    for (int w2 = 0; w2 < WMAX; ++w2) {
        const int base = w2 * 64;
        aliveW[w2] = (m > base)
                   ? ((m - base >= 64) ? ~0ull : ((1ull << (m - base)) - 1ull))
                   : 0ull;
    }

    int need_slow = 0;
    for (int t = 0; t < maxo; ++t) {
        // lane-local find of lowest-rank alive candidate (no shfl)
        int w = WMAX; u64 cw = 0ull;
        #pragma unroll
        for (int q = WMAX - 1; q >= 0; --q)
            if (aliveW[q] != 0ull) { w = q; cw = aliveW[q]; }
        if (w == WMAX) {                     // exhausted
            if (rem > 0) need_slow = 1;
            break;
        }
        const int bit = __builtin_ctzll(cw);
        const int r   = w * 64 + bit;

        const u64 kr = skey[r];              // uniform -> broadcast
        const int n  = NMS_N - 1 - (int)((kr >> 18) & 0x3FFFull);
        const int sr = (int)(kr & 0x1FFull);
        if (lane == 0) {
            if (OUT64) {
                out64[t * 3 + 0] = (long long)b;
                out64[t * 3 + 1] = (long long)c;
                out64[t * 3 + 2] = (long long)n;
            } else {
                out32[t * 3 + 0] = b;
                out32[t * 3 + 1] = c;
                out32[t * 3 + 2] = n;
            }
        }
        const float4 A = make_float4(sx[sr], sy[sr], sz[sr], sw[sr]);  // uniform
        const float areaA = __fmul_rn(__fsub_rn(A.z, A.x), __fsub_rn(A.w, A.y));

        // suppression row: register IoU + ballot per word; self-kill folded in
        #pragma unroll
        for (int w2 = 0; w2 < WMAX; ++w2) {
            const bool valid = (w2 * 64 + lane) < m;
            const bool sup = valid &&
                (iou_pre(A, areaA, bxc[w2], areaBc[w2]) > iou_thr);
            u64 kill = __ballot(sup);
            if (w2 == w) kill |= (1ull << bit);   // self (zero-area safe)
            aliveW[w2] &= ~kill;
        }
    }
    if (lane == 0) flags[bc] = need_slow;
}

// ---- slow exact fallback (verified round-2 structure, flag-gated) ----
__device__ __forceinline__ int bucketf(float s) {
    int v = (int)__float_as_uint(s) - 0x3F000000;
    v >>= 15;
    return v < 0 ? 0 : (v > 255 ? 255 : v);
}

template <bool OUT64>
__global__ __launch_bounds__(NTHREADS) void nms_slow(
    const float* __restrict__ boxes,
    const float* __restrict__ scores,
    const int* __restrict__ p_maxout,
    const float* __restrict__ p_iou,
    const float* __restrict__ p_sthr,
    void* __restrict__ out_raw,
    const int* __restrict__ flags)
{
    __shared__ int    hist[NBUCK];
    __shared__ u64    key[SCAP];
    __shared__ float4 cbox[SCAP];
    __shared__ float4 selbox[NMS_MAX_OUT];
    __shared__ u64    s_wmax[NTHREADS / 64];
    __shared__ u64    s_best;
    __shared__ int    s_cnt, s_cutLo, s_cutHi, s_rem, s_state;

    const int tid = threadIdx.x;
    const int bc  = blockIdx.x;
    if (flags && flags[bc] == 0) return;     // uniform exit before any barrier
    const int b   = bc / NMS_C;
    const int c   = bc % NMS_C;

    const float score_thr = p_sthr[0];
    const float iou_thr   = p_iou[0];
    int maxo = p_maxout[0];
    if (maxo > NMS_MAX_OUT) maxo = NMS_MAX_OUT;
    if (maxo < 0) maxo = 0;

    int*       out32 = (int*)out_raw       + (size_t)bc * NMS_MAX_OUT * 3;
    long long* out64 = (long long*)out_raw + (size_t)bc * NMS_MAX_OUT * 3;
    for (int i = tid; i < NMS_MAX_OUT * 3; i += NTHREADS) {
        if (OUT64) out64[i] = -1LL; else out32[i] = -1;
    }

    const float*  sc      = scores + ((size_t)b * NMS_C + c) * NMS_N;
    const float4* sc4     = (const float4*)sc;
    const float4* boxes_b = (const float4*)(boxes + (size_t)b * NMS_N * 4);

    for (int i = tid; i < NBUCK; i += NTHREADS) hist[i] = 0;
    if (tid == 0) s_cnt = 0;
    __syncthreads();
    for (int i = tid; i < NMS_N / 4; i += NTHREADS) {
        float4 s4 = sc4[i];
        float ss[4] = {s4.x, s4.y, s4.z, s4.w};
        #pragma unroll
        for (int j = 0; j < 4; ++j)
            if (ss[j] > score_thr) atomicAdd(&hist[bucketf(ss[j])], 1);
    }
    __syncthreads();

    if (tid == 0) {
        int cum = 0, cut = NBUCK;
        for (int bk = NBUCK - 1; bk >= 0; --bk) {
            int h = hist[bk];
            if (cum > 0 && cum + h > SCAP) break;
            cum += h; cut = bk;
            if (cum >= T_MIN) break;
        }
        s_cutLo = cut; s_cutHi = NBUCK - 1;
        int rem = 0;
        for (int bk = 0; bk < cut; ++bk) rem += hist[bk];
        s_rem = rem;
    }
    __syncthreads();

    auto compact = [&](int lo, int hi) {
        for (int i = tid; i < NMS_N / 4; i += NTHREADS) {
            float4 s4 = sc4[i];
            float ss[4] = {s4.x, s4.y, s4.z, s4.w};
            #pragma unroll
            for (int j = 0; j < 4; ++j) {
                float s = ss[j];
                if (s > score_thr) {
                    int bk = bucketf(s);
                    if (bk >= lo && bk <= hi) {
                        int n = i * 4 + j;
                        int p = atomicAdd(&s_cnt, 1);
                        if (p < SCAP) {
                            key[p] = ((u64)__float_as_uint(s) << 24)
                                   | ((u64)(NMS_N - 1 - n) << 10)
                                   | (u64)p;
                            cbox[p] = boxes_b[n];
                        }
                    }
                }
            }
        }
    };
    compact(s_cutLo, s_cutHi);
    __syncthreads();

    int t = 0;
    while (t < maxo) {
        int m = s_cnt; if (m > SCAP) m = SCAP;
        u64 lmax = 0ull;
        for (int i = tid; i < m; i += NTHREADS) {
            u64 k = key[i];
            if (k > lmax) lmax = k;
        }
        #pragma unroll
        for (int off = 32; off > 0; off >>= 1) {
            u64 o = __shfl_down(lmax, off);
            if (o > lmax) lmax = o;
        }
        if ((tid & 63) == 0) s_wmax[tid >> 6] = lmax;
        __syncthreads();
        if (tid == 0) {
            u64 best = s_wmax[0];
            #pragma unroll
            for (int w = 1; w < NTHREADS / 64; ++w)
                if (s_wmax[w] > best) best = s_wmax[w];
            s_best = best;
            if (best) {
                int slot = (int)(best & 0x3FFull);
                int n    = NMS_N - 1 - (int)((best >> 10) & 0x3FFFull);
                key[slot] = 0ull;
                if (OUT64) {
                    out64[t * 3 + 0] = (long long)b;
                    out64[t * 3 + 1] = (long long)c;
                    out64[t * 3 + 2] = (long long)n;
                } else {
                    out32[t * 3 + 0] = b;
                    out32[t * 3 + 1] = c;
                    out32[t * 3 + 2] = n;
                }
                selbox[t] = cbox[slot];
                s_state = 0;
            } else if (s_rem == 0) {
                s_state = 2;
            } else {
                int hiB = s_cutLo - 1;
                int cum = 0, cut = hiB + 1;
                for (int bk = hiB; bk >= 0; --bk) {
                    int h = hist[bk];
                    if (cum > 0 && cum + h > SCAP) break;
                    cum += h; cut = bk;
                    if (cum >= T_MIN) break;
                }
                s_cutLo = cut; s_cutHi = hiB;
                int rem = 0;
                for (int bk = 0; bk < cut; ++bk) rem += hist[bk];
                s_rem = rem;
                s_cnt = 0;
                s_state = 1;
            }
        }
        __syncthreads();

        if (s_state == 2) break;

        if (s_state == 0) {
            const float4 A = selbox[t];
            const float areaA = __fmul_rn(__fsub_rn(A.z, A.x), __fsub_rn(A.w, A.y));
            int m0 = s_cnt; if (m0 > SCAP) m0 = SCAP;
            for (int i = tid; i < m0; i += NTHREADS) {
                u64 k = key[i];
                if (!k) continue;
                if (iou_exact(A, areaA, cbox[i]) > iou_thr) key[i] = 0ull;
            }
            __syncthreads();
            ++t;
        } else {
            compact(s_cutLo, s_cutHi);
            __syncthreads();
            int m2 = s_cnt; if (m2 > SCAP) m2 = SCAP;
            for (int i = tid; i < m2; i += NTHREADS) {
                u64 k = key[i];
                if (!k) continue;
                float4 Bx = cbox[i];
                for (int j = 0; j < t; ++j) {
                    float4 A = selbox[j];
                    float areaA = __fmul_rn(__fsub_rn(A.z, A.x), __fsub_rn(A.w, A.y));
                    if (iou_exact(A, areaA, Bx) > iou_thr) { key[i] = 0ull; break; }
                }
            }
            __syncthreads();
        }
    }
}

extern "C" void kernel_launch(void* const* d_in, const int* in_sizes, int n_in,
                              void* d_out, int out_size, void* d_ws, size_t ws_size,
                              hipStream_t stream) {
    const float* boxes  = (const float*)d_in[0];
    const float* scores = (const float*)d_in[1];
    const int*   p_maxo = (const int*)d_in[2];
    const float* p_iou  = (const float*)d_in[3];
    const float* p_sthr = (const float*)d_in[4];

    const dim3 grid(NMS_B * NMS_C);
    const dim3 block(NTHREADS);
    const bool out64 = (out_size == NMS_B * NMS_C * NMS_MAX_OUT * 3 * 2);

    int* flags = (ws_size >= (size_t)NMS_B * NMS_C * sizeof(int)) ? (int*)d_ws : nullptr;

    if (out64) {
        if (flags)
            hipLaunchKernelGGL(nms_fast<true>, grid, block, 0, stream,
                               boxes, scores, p_maxo, p_iou, p_sthr, d_out, flags);
        hipLaunchKernelGGL(nms_slow<true>, grid, block, 0, stream,
                           boxes, scores, p_maxo, p_iou, p_sthr, d_out, flags);
    } else {
        if (flags)
            hipLaunchKernelGGL(nms_fast<false>, grid, block, 0, stream,
                               boxes, scores, p_maxo, p_iou, p_sthr, d_out, flags);
        hipLaunchKernelGGL(nms_slow<false>, grid, block, 0, stream,
                           boxes, scores, p_maxo, p_iou, p_sthr, d_out, flags);
    }
}